// Round 1
// baseline (47.907 us; speedup 1.0000x reference)
//
#include <hip/hip_runtime.h>

#define B_   16
#define T_   10
#define D_   256
#define MI_  32
#define MO_  16
#define RES_ 200

__global__ __launch_bounds__(256) void spectral_fused(
    const float* __restrict__ v,
    const float* __restrict__ w_real,
    const float* __restrict__ w_imag,
    float* __restrict__ out)
{
    const int bt = blockIdx.x;      // 0..159  (b*T_ + t)
    const int t  = bt % T_;
    const int d  = threadIdx.x;     // 0..255  (h)

    __shared__ float s_wr[MO_ * MI_];
    __shared__ float s_wi[MO_ * MI_];
    __shared__ float s_trig[RES_][2 * MO_];  // [x][0..15]=cos, [x][16..31]=-sin

    // --- Phase 1: stage weights + build trig table -------------------------
    const float* wrt = w_real + t * MO_ * MI_;
    const float* wit = w_imag + t * MO_ * MI_;
    for (int idx = threadIdx.x; idx < MO_ * MI_; idx += 256) {
        s_wr[idx] = wrt[idx];
        s_wi[idx] = wit[idx];
    }
    // theta[o][x] = 2*pi*o*x/200 exactly (fftfreq d=1/199 cancels linspace 1/199)
    for (int idx = threadIdx.x; idx < RES_ * MO_; idx += 256) {
        int x = idx >> 4;
        int o = idx & 15;
        int k = (o * x) % RES_;                     // reduce angle for accuracy
        float ang = 6.28318530717958647692f * ((float)k * (1.0f / (float)RES_));
        float sv, cv;
        __sincosf(ang, &sv, &cv);
        s_trig[x][o]       = cv;
        s_trig[x][o + MO_] = -sv;
    }
    __syncthreads();

    // --- Phase 2: per-thread complex contraction C,S over MODES_IN ---------
    float rr[MI_], ii[MI_];
    const float4* vp = reinterpret_cast<const float4*>(
        v + (size_t)(bt * D_ + d) * (2 * MI_));
    #pragma unroll
    for (int j = 0; j < MI_ / 4; ++j) {
        float4 q = vp[j];
        rr[4*j+0]=q.x; rr[4*j+1]=q.y; rr[4*j+2]=q.z; rr[4*j+3]=q.w;
    }
    #pragma unroll
    for (int j = 0; j < MI_ / 4; ++j) {
        float4 q = vp[MI_/4 + j];
        ii[4*j+0]=q.x; ii[4*j+1]=q.y; ii[4*j+2]=q.z; ii[4*j+3]=q.w;
    }

    float C[MO_], S[MO_];
    #pragma unroll
    for (int o = 0; o < MO_; ++o) {
        float c = 0.f, s = 0.f;
        #pragma unroll
        for (int m = 0; m < MI_; ++m) {
            float a = s_wr[o * MI_ + m];   // wave-uniform -> LDS broadcast
            float b = s_wi[o * MI_ + m];
            c = fmaf(rr[m], a, c);
            c = fmaf(-ii[m], b, c);
            s = fmaf(rr[m], b, s);
            s = fmaf(ii[m], a, s);
        }
        C[o] = c;
        S[o] = s;
    }

    // --- Phase 3: inverse transform along x, coalesced stores --------------
    float* op = out + (size_t)bt * RES_ * D_ + d;
    for (int x = 0; x < RES_; ++x) {
        float acc = 0.f;
        #pragma unroll
        for (int o = 0; o < MO_; ++o) {
            acc = fmaf(C[o], s_trig[x][o],       acc);
            acc = fmaf(S[o], s_trig[x][o + MO_], acc);   // -sin already folded
        }
        op[(size_t)x * D_] = acc;
    }
}

extern "C" void kernel_launch(void* const* d_in, const int* in_sizes, int n_in,
                              void* d_out, int out_size, void* d_ws, size_t ws_size,
                              hipStream_t stream) {
    const float* v  = (const float*)d_in[0];
    const float* wr = (const float*)d_in[1];
    const float* wi = (const float*)d_in[2];
    float* out = (float*)d_out;
    spectral_fused<<<B_ * T_, 256, 0, stream>>>(v, wr, wi, out);
}

// Round 2
// 35.811 us; speedup vs baseline: 1.3378x; 1.3378x over previous
//
#include <hip/hip_runtime.h>

#define B_   16
#define T_   10
#define D_   256
#define MI_  32
#define MO_  16
#define RES_ 200
#define XCHUNK 20
#define NCHUNK (RES_ / XCHUNK)          // 10
#define CS_STRIDE (2 * MO_ * D_)        // 8192 floats per bt
#define CS_BYTES ((size_t)B_ * T_ * CS_STRIDE * sizeof(float))  // 5.24 MB

// ---------- Kernel A: complex contraction -> C,S planes in ws --------------
__global__ __launch_bounds__(256) void spectral_cs(
    const float* __restrict__ v,
    const float* __restrict__ w_real,
    const float* __restrict__ w_imag,
    float* __restrict__ ws)
{
    const int bt = blockIdx.x;      // 0..159
    const int t  = bt % T_;
    const int d  = threadIdx.x;     // h

    __shared__ float s_wr[MO_ * MI_];
    __shared__ float s_wi[MO_ * MI_];
    const float* wrt = w_real + t * MO_ * MI_;
    const float* wit = w_imag + t * MO_ * MI_;
    for (int idx = threadIdx.x; idx < MO_ * MI_; idx += 256) {
        s_wr[idx] = wrt[idx];
        s_wi[idx] = wit[idx];
    }
    __syncthreads();

    float rr[MI_], ii[MI_];
    const float4* vp = reinterpret_cast<const float4*>(
        v + (size_t)(bt * D_ + d) * (2 * MI_));
    #pragma unroll
    for (int j = 0; j < MI_ / 4; ++j) {
        float4 q = vp[j];
        rr[4*j+0]=q.x; rr[4*j+1]=q.y; rr[4*j+2]=q.z; rr[4*j+3]=q.w;
    }
    #pragma unroll
    for (int j = 0; j < MI_ / 4; ++j) {
        float4 q = vp[MI_/4 + j];
        ii[4*j+0]=q.x; ii[4*j+1]=q.y; ii[4*j+2]=q.z; ii[4*j+3]=q.w;
    }

    float* wsp = ws + (size_t)bt * CS_STRIDE;
    #pragma unroll
    for (int o = 0; o < MO_; ++o) {
        float c = 0.f, s = 0.f;
        #pragma unroll
        for (int m = 0; m < MI_; ++m) {
            float a = s_wr[o * MI_ + m];
            float b = s_wi[o * MI_ + m];
            c = fmaf(rr[m], a, c);
            c = fmaf(-ii[m], b, c);
            s = fmaf(rr[m], b, s);
            s = fmaf(ii[m], a, s);
        }
        wsp[o * D_ + d]          = c;   // C plane o  (coalesced)
        wsp[(MO_ + o) * D_ + d]  = s;   // S plane o
    }
}

// ---------- Kernel B: inverse transform, x-parallel ------------------------
__global__ __launch_bounds__(256) void spectral_ift(
    const float* __restrict__ ws,
    float* __restrict__ out)
{
    const int blk   = blockIdx.x;          // 0..1599
    const int bt    = blk / NCHUNK;
    const int x0    = (blk % NCHUNK) * XCHUNK;
    const int d     = threadIdx.x;         // h

    __shared__ float s_trig[XCHUNK][2 * MO_];  // [xl][0..15]=cos, [16..31]=-sin

    for (int idx = threadIdx.x; idx < XCHUNK * MO_; idx += 256) {
        int xl = idx >> 4;
        int o  = idx & 15;
        int k  = (o * (x0 + xl)) % RES_;
        float ang = 6.28318530717958647692f * ((float)k * (1.0f / (float)RES_));
        float sv, cv;
        __sincosf(ang, &sv, &cv);
        s_trig[xl][o]       = cv;
        s_trig[xl][o + MO_] = -sv;
    }

    // coalesced C,S register load (32 plane reads)
    const float* wsp = ws + (size_t)bt * CS_STRIDE;
    float C[MO_], S[MO_];
    #pragma unroll
    for (int o = 0; o < MO_; ++o) {
        C[o] = wsp[o * D_ + d];
        S[o] = wsp[(MO_ + o) * D_ + d];
    }
    __syncthreads();

    float* op = out + ((size_t)bt * RES_ + x0) * D_ + d;
    #pragma unroll
    for (int xl = 0; xl < XCHUNK; ++xl) {
        float acc = 0.f;
        #pragma unroll
        for (int o = 0; o < MO_; ++o) {
            acc = fmaf(C[o], s_trig[xl][o],       acc);
            acc = fmaf(S[o], s_trig[xl][o + MO_], acc);  // -sin folded
        }
        op[(size_t)xl * D_] = acc;
    }
}

// ---------- Fallback (ws too small): original fused kernel -----------------
__global__ __launch_bounds__(256) void spectral_fused(
    const float* __restrict__ v,
    const float* __restrict__ w_real,
    const float* __restrict__ w_imag,
    float* __restrict__ out)
{
    const int bt = blockIdx.x;
    const int t  = bt % T_;
    const int d  = threadIdx.x;

    __shared__ float s_wr[MO_ * MI_];
    __shared__ float s_wi[MO_ * MI_];
    __shared__ float s_trig[RES_][2 * MO_];

    const float* wrt = w_real + t * MO_ * MI_;
    const float* wit = w_imag + t * MO_ * MI_;
    for (int idx = threadIdx.x; idx < MO_ * MI_; idx += 256) {
        s_wr[idx] = wrt[idx];
        s_wi[idx] = wit[idx];
    }
    for (int idx = threadIdx.x; idx < RES_ * MO_; idx += 256) {
        int x = idx >> 4;
        int o = idx & 15;
        int k = (o * x) % RES_;
        float ang = 6.28318530717958647692f * ((float)k * (1.0f / (float)RES_));
        float sv, cv;
        __sincosf(ang, &sv, &cv);
        s_trig[x][o]       = cv;
        s_trig[x][o + MO_] = -sv;
    }
    __syncthreads();

    float rr[MI_], ii[MI_];
    const float4* vp = reinterpret_cast<const float4*>(
        v + (size_t)(bt * D_ + d) * (2 * MI_));
    #pragma unroll
    for (int j = 0; j < MI_ / 4; ++j) {
        float4 q = vp[j];
        rr[4*j+0]=q.x; rr[4*j+1]=q.y; rr[4*j+2]=q.z; rr[4*j+3]=q.w;
    }
    #pragma unroll
    for (int j = 0; j < MI_ / 4; ++j) {
        float4 q = vp[MI_/4 + j];
        ii[4*j+0]=q.x; ii[4*j+1]=q.y; ii[4*j+2]=q.z; ii[4*j+3]=q.w;
    }

    float C[MO_], S[MO_];
    #pragma unroll
    for (int o = 0; o < MO_; ++o) {
        float c = 0.f, s = 0.f;
        #pragma unroll
        for (int m = 0; m < MI_; ++m) {
            float a = s_wr[o * MI_ + m];
            float b = s_wi[o * MI_ + m];
            c = fmaf(rr[m], a, c);
            c = fmaf(-ii[m], b, c);
            s = fmaf(rr[m], b, s);
            s = fmaf(ii[m], a, s);
        }
        C[o] = c;
        S[o] = s;
    }

    float* op = out + (size_t)bt * RES_ * D_ + d;
    for (int x = 0; x < RES_; ++x) {
        float acc = 0.f;
        #pragma unroll
        for (int o = 0; o < MO_; ++o) {
            acc = fmaf(C[o], s_trig[x][o],       acc);
            acc = fmaf(S[o], s_trig[x][o + MO_], acc);
        }
        op[(size_t)x * D_] = acc;
    }
}

extern "C" void kernel_launch(void* const* d_in, const int* in_sizes, int n_in,
                              void* d_out, int out_size, void* d_ws, size_t ws_size,
                              hipStream_t stream) {
    const float* v  = (const float*)d_in[0];
    const float* wr = (const float*)d_in[1];
    const float* wi = (const float*)d_in[2];
    float* out = (float*)d_out;

    if (ws_size >= CS_BYTES) {
        float* ws = (float*)d_ws;
        spectral_cs <<<B_ * T_,          256, 0, stream>>>(v, wr, wi, ws);
        spectral_ift<<<B_ * T_ * NCHUNK, 256, 0, stream>>>(ws, out);
    } else {
        spectral_fused<<<B_ * T_, 256, 0, stream>>>(v, wr, wi, out);
    }
}